// Round 9
// baseline (294.709 us; speedup 1.0000x reference)
//
#include <hip/hip_runtime.h>
#include <hip/hip_fp16.h>

#define IN_C 128
#define H1   256
#define H2   32
#define BWL  8              // bucket width = 256 nodes
#define NBMAX 256           // max buckets (N <= 65536)

typedef _Float16 half8 __attribute__((ext_vector_type(8)));
typedef _Float16 half4 __attribute__((ext_vector_type(4)));
typedef _Float16 h2    __attribute__((ext_vector_type(2)));
typedef float f32x4 __attribute__((ext_vector_type(4)));

// ---------------- init: zero bucket counters ----------------
__global__ __launch_bounds__(256) void k_init(int* bucket_cnt, int* bucket_cursor, int nb) {
  int i = blockIdx.x * blockDim.x + threadIdx.x;
  if (i < nb) { bucket_cnt[i] = 0; bucket_cursor[i] = 0; }
}

// ---------------- cast+scale x: xh[node] = (fp16)(x[node] * dinv[node])  (runs AFTER fill2) ----------------
__global__ __launch_bounds__(256) void k_cast(const float4* __restrict__ x4, const float* __restrict__ dinv,
                                              h2* __restrict__ xh, int n4) {
  int i = blockIdx.x * 256 + threadIdx.x;
  if (i < n4) {
    float4 v = x4[i];
    float dn = dinv[i >> 5];                 // 32 float4 per node (IN_C=128)
    h2 a, b;
    a[0] = (_Float16)(v.x * dn); a[1] = (_Float16)(v.y * dn);
    b[0] = (_Float16)(v.z * dn); b[1] = (_Float16)(v.w * dn);
    xh[2 * i] = a; xh[2 * i + 1] = b;
  }
}

// ---------------- cast weights into MFMA-fragment-swizzled fp16 layout ----------------
__global__ __launch_bounds__(256) void k_castw(const float* __restrict__ W1, const float* __restrict__ W2,
                                               _Float16* __restrict__ W1s, _Float16* __restrict__ W2s) {
  int i = blockIdx.x * 256 + threadIdx.x;
  if (i < 128 * 256) {
    int d = i >> 3, j = i & 7;
    int mrow = d & 15, quad = (d >> 4) & 3, ks = (d >> 6) & 3, nt = d >> 8;
    W1s[i] = (_Float16)W1[(ks * 32 + quad * 8 + j) * 256 + nt * 16 + mrow];
  }
  if (i < 32 * 256) {
    int d = i >> 3, j = i & 7;
    int mrow = d & 15, quad = (d >> 4) & 3, ks = (d >> 6) & 7, nt = d >> 9;
    W2s[i] = (_Float16)W2[(ks * 32 + quad * 8 + j) * 32 + nt * 16 + mrow];
  }
}

// ---------------- bucket histogram only (NO global per-node atomics) ----------------
__global__ __launch_bounds__(256) void k_bin(const int* __restrict__ dst, int* bucket_cnt, int e, int nb) {
  __shared__ int hist[NBMAX];
  for (int u = threadIdx.x; u < nb; u += 256) hist[u] = 0;
  __syncthreads();
  int base = blockIdx.x * 2048;
  #pragma unroll
  for (int j = 0; j < 8; j++) {
    int i = base + j * 256 + threadIdx.x;
    if (i < e) atomicAdd(&hist[dst[i] >> BWL], 1);
  }
  __syncthreads();
  for (int u = threadIdx.x; u < nb; u += 256) if (hist[u]) atomicAdd(&bucket_cnt[u], hist[u]);
}

// ---------------- scan bucket counts -> bucket_base (1 block) ----------------
__global__ __launch_bounds__(256) void k_scan_bkt(const int* __restrict__ bucket_cnt,
                                                  int* __restrict__ bucket_base, int nb) {
  __shared__ int tmp[256];
  int t = threadIdx.x;
  int b = (t < nb) ? bucket_cnt[t] : 0;
  tmp[t] = b; __syncthreads();
  for (int off = 1; off < 256; off <<= 1) {
    int x = (t >= off) ? tmp[t - off] : 0;
    __syncthreads();
    tmp[t] += x;
    __syncthreads();
  }
  if (t < nb) bucket_base[t] = tmp[t] - b;
  if (t == 255) bucket_base[nb] = tmp[255];
}

// ---------------- binned partition: (src,dst) packed 8B ----------------
__global__ __launch_bounds__(256) void k_scatter(const int* __restrict__ src, const int* __restrict__ dst,
                                                 const int* __restrict__ bucket_base, int* bucket_cursor,
                                                 unsigned long long* __restrict__ binned, int e, int nb) {
  __shared__ int hist[NBMAX];
  __shared__ int wbase[NBMAX];
  int t = threadIdx.x;
  for (int u = t; u < nb; u += 256) hist[u] = 0;
  __syncthreads();
  int base = blockIdx.x * 4096;
  int s_[16], d_[16];
  #pragma unroll
  for (int j = 0; j < 16; j++) {
    int i = base + j * 256 + t;
    if (i < e) {
      s_[j] = src[i]; d_[j] = dst[i];
      atomicAdd(&hist[d_[j] >> BWL], 1);
    } else d_[j] = -1;
  }
  __syncthreads();
  for (int u = t; u < nb; u += 256) {
    int c = hist[u];
    wbase[u] = (c > 0) ? (bucket_base[u] + atomicAdd(&bucket_cursor[u], c)) : 0;
  }
  __syncthreads();
  for (int u = t; u < nb; u += 256) hist[u] = 0;
  __syncthreads();
  #pragma unroll
  for (int j = 0; j < 16; j++) {
    if (d_[j] >= 0) {
      int b = d_[j] >> BWL;
      int r = atomicAdd(&hist[b], 1);
      binned[wbase[b] + r] = ((unsigned long long)(unsigned)d_[j] << 32) | (unsigned)s_[j];
    }
  }
}

// ---------------- CSR fill: one block/bucket. LDS degree count + prefix -> offsets/ecnt/dinv, place edges ----------------
__global__ __launch_bounds__(256) void k_fill2(const unsigned long long* __restrict__ binned,
                                               const int* __restrict__ bucket_base,
                                               int* __restrict__ csr_src,
                                               int* __restrict__ offsets, int* __restrict__ ecnt,
                                               float* __restrict__ dinv, int n, int nb) {
  __shared__ int cnt[256], pre[256], cur[256], loc[256];
  int b = blockIdx.x;
  int t = threadIdx.x;
  cnt[t] = 0; cur[t] = 0;
  __syncthreads();
  int start = bucket_base[b], end = bucket_base[b + 1];
  int node0 = b << BWL;
  for (int i = start + t; i < end; i += 256) {
    int d = (int)(binned[i] >> 32);
    atomicAdd(&cnt[d - node0], 1);
  }
  __syncthreads();
  int v = cnt[t];
  pre[t] = v; __syncthreads();
  for (int off = 1; off < 256; off <<= 1) {
    int x = (t >= off) ? pre[t - off] : 0;
    __syncthreads();
    pre[t] += x;
    __syncthreads();
  }
  int excl = pre[t] - v;
  loc[t] = excl;
  int node = node0 + t;
  if (node < n) {
    offsets[node] = start + excl;
    ecnt[node] = v;
    dinv[node] = rsqrtf((float)(v + 1));
  }
  __syncthreads();
  for (int i = start + t; i < end; i += 256) {
    unsigned long long sd = binned[i];
    int s = (int)(sd & 0xffffffffULL), d = (int)(sd >> 32);
    int li = d - node0;
    int p = atomicAdd(&cur[li], 1);
    csr_src[start + loc[li] + p] = s;
  }
}

// ---------------- layer-1 aggregation: wave/node; 4 edge-groups x 16 lanes; half8 (16B) gathers ----------------
__global__ __launch_bounds__(256) void k_agg1(const half8* __restrict__ xh8, const float* __restrict__ dinv,
                                              const int* __restrict__ ecnt, const int* __restrict__ offsets,
                                              const int* __restrict__ csr_src,
                                              half8* __restrict__ aggh8, int n) {
  int node = blockIdx.x * 4 + (threadIdx.x >> 6);
  int lane = threadIdx.x & 63;
  int g = lane >> 4;            // edge group 0..3
  int c8 = lane & 15;           // half8 index: channels c8*8..c8*8+7
  if (node >= n) return;
  float acc[8];
  #pragma unroll
  for (int k = 0; k < 8; k++) acc[k] = 0.f;
  int start = offsets[node];
  int cnt = ecnt[node];
  int j = 0;
  for (; j + 16 <= cnt; j += 16) {          // 16 edges/chunk: 4 per group
    int sA = csr_src[start + j + g];
    int sB = csr_src[start + j + 4 + g];
    int sC = csr_src[start + j + 8 + g];
    int sD = csr_src[start + j + 12 + g];
    half8 vA = xh8[(size_t)sA * 16 + c8];   // 16B/lane, 4 rows per instr
    half8 vB = xh8[(size_t)sB * 16 + c8];
    half8 vC = xh8[(size_t)sC * 16 + c8];
    half8 vD = xh8[(size_t)sD * 16 + c8];
    half8 s = (vA + vB) + (vC + vD);        // depth-2 fp16 tree
    #pragma unroll
    for (int k = 0; k < 8; k++) acc[k] += (float)s[k];
  }
  for (int t = j + g; t < cnt; t += 4) {    // tail: group-strided
    half8 v = xh8[(size_t)csr_src[start + t] * 16 + c8];
    #pragma unroll
    for (int k = 0; k < 8; k++) acc[k] += (float)v[k];
  }
  #pragma unroll
  for (int k = 0; k < 8; k++) {             // cross-group reduce (bits 4,5)
    acc[k] += __shfl_xor(acc[k], 16, 64);
    acc[k] += __shfl_xor(acc[k], 32, 64);
  }
  if (g == 0) {
    half8 selfv = xh8[(size_t)node * 16 + c8];
    float dn = dinv[node];
    half8 o;
    #pragma unroll
    for (int k = 0; k < 8; k++) o[k] = (_Float16)((acc[k] + (float)selfv[k]) * dn);
    aggh8[(size_t)node * 16 + c8] = o;
  }
}

// ---------------- GEMM1 (MFMA): h1 = relu(agg1 @ W1 + b1). B frags lane-contiguous from swizzled W1s ----------------
__global__ __launch_bounds__(256) void k_gemm1(const _Float16* __restrict__ aggh,
                                               const _Float16* __restrict__ W1s, const float* __restrict__ b1,
                                               _Float16* __restrict__ h1h, int n) {
  int wid = threadIdx.x >> 6, lane = threadIdx.x & 63;
  int quad = lane >> 4, mrow = lane & 15;
  int mbase = blockIdx.x * 64 + wid * 16;
  int node = mbase + mrow; if (node >= n) node = n - 1;   // clamp: garbage rows never stored
  const half8* A = (const half8*)aggh;                    // [node][k] ; 16 half8 per row
  const half8* B = (const half8*)W1s;                     // swizzled: frag(nt,ks) at [(nt*4+ks)*64 + lane]
  f32x4 acc[16];
  #pragma unroll
  for (int t = 0; t < 16; t++) acc[t] = (f32x4){0.f, 0.f, 0.f, 0.f};
  #pragma unroll
  for (int ks = 0; ks < 4; ks++) {                        // K = 4 x 32
    half8 a = A[(size_t)node * 16 + ks * 4 + quad];       // A[m=lane&15][k=quad*8+j]
    #pragma unroll
    for (int nt = 0; nt < 16; nt++) {
      half8 b = B[(nt * 4 + ks) * 64 + lane];             // coalesced 1KB load, L2-resident
      acc[nt] = __builtin_amdgcn_mfma_f32_16x16x32_f16(a, b, acc[nt], 0, 0, 0);
    }
  }
  #pragma unroll
  for (int nt = 0; nt < 16; nt++) {
    int c = nt * 16 + mrow;                               // C/D: col = lane&15
    float bias = b1[c];
    #pragma unroll
    for (int r = 0; r < 4; r++) {
      int m = mbase + quad * 4 + r;                       // C/D: row = quad*4 + reg
      if (m < n) h1h[(size_t)m * H1 + c] = (_Float16)fmaxf(acc[nt][r] + bias, 0.f);
    }
  }
}

// ---------------- GEMM2 (MFMA): h2~ = (h1 @ W2) * dinv[m]. B frags from swizzled W2s ----------------
__global__ __launch_bounds__(256) void k_gemm2(const _Float16* __restrict__ h1h,
                                               const _Float16* __restrict__ W2s, const float* __restrict__ dinv,
                                               _Float16* __restrict__ h2h, int n) {
  int wid = threadIdx.x >> 6, lane = threadIdx.x & 63;
  int quad = lane >> 4, mrow = lane & 15;
  int mbase = blockIdx.x * 64 + wid * 16;
  int node = mbase + mrow; if (node >= n) node = n - 1;
  const half8* A = (const half8*)h1h;                     // [node][k] ; 32 half8 per row
  const half8* B = (const half8*)W2s;                     // swizzled: frag(nt,ks) at [(nt*8+ks)*64 + lane]
  f32x4 acc[2];
  acc[0] = (f32x4){0.f, 0.f, 0.f, 0.f};
  acc[1] = (f32x4){0.f, 0.f, 0.f, 0.f};
  #pragma unroll
  for (int ks = 0; ks < 8; ks++) {                        // K = 8 x 32
    half8 a = A[(size_t)node * 32 + ks * 4 + quad];
    #pragma unroll
    for (int nt = 0; nt < 2; nt++) {
      half8 b = B[(nt * 8 + ks) * 64 + lane];             // coalesced, 16KB table L1-resident
      acc[nt] = __builtin_amdgcn_mfma_f32_16x16x32_f16(a, b, acc[nt], 0, 0, 0);
    }
  }
  #pragma unroll
  for (int nt = 0; nt < 2; nt++) {
    int c = nt * 16 + mrow;
    #pragma unroll
    for (int r = 0; r < 4; r++) {
      int m = mbase + quad * 4 + r;
      if (m < n) h2h[(size_t)m * H2 + c] = (_Float16)(acc[nt][r] * dinv[m]);  // pre-scaled for agg2
    }
  }
}

// ---------------- layer-2 aggregation: wave/node; 8 edge-groups x 8 lanes; half4 (8B) gathers ----------------
__global__ __launch_bounds__(256) void k_agg2(const half4* __restrict__ h2h4, const float* __restrict__ dinv,
                                              const int* __restrict__ ecnt, const int* __restrict__ offsets,
                                              const int* __restrict__ csr_src,
                                              const float* __restrict__ b2, half4* __restrict__ zh4, int n) {
  int node = blockIdx.x * 4 + (threadIdx.x >> 6);
  int lane = threadIdx.x & 63;
  int g = lane >> 3;            // edge group 0..7
  int c4 = lane & 7;            // half4 index: channels c4*4..c4*4+3
  if (node >= n) return;
  float acc[4];
  #pragma unroll
  for (int k = 0; k < 4; k++) acc[k] = 0.f;
  int start = offsets[node];
  int cnt = ecnt[node];
  int j = 0;
  for (; j + 16 <= cnt; j += 16) {          // 16 edges/chunk: 2 per group
    int sA = csr_src[start + j + g];
    int sB = csr_src[start + j + 8 + g];
    half4 vA = h2h4[(size_t)sA * 8 + c4];
    half4 vB = h2h4[(size_t)sB * 8 + c4];
    half4 s = vA + vB;
    #pragma unroll
    for (int k = 0; k < 4; k++) acc[k] += (float)s[k];
  }
  for (int t = j + g; t < cnt; t += 8) {
    half4 v = h2h4[(size_t)csr_src[start + t] * 8 + c4];
    #pragma unroll
    for (int k = 0; k < 4; k++) acc[k] += (float)v[k];
  }
  #pragma unroll
  for (int k = 0; k < 4; k++) {             // cross-group reduce (bits 3,4,5)
    acc[k] += __shfl_xor(acc[k], 8, 64);
    acc[k] += __shfl_xor(acc[k], 16, 64);
    acc[k] += __shfl_xor(acc[k], 32, 64);
  }
  if (g == 0) {
    half4 selfv = h2h4[(size_t)node * 8 + c4];
    float dn = dinv[node];
    half4 o;
    #pragma unroll
    for (int k = 0; k < 4; k++) o[k] = (_Float16)((acc[k] + (float)selfv[k]) * dn + b2[c4 * 4 + k]);
    zh4[(size_t)node * 8 + c4] = o;
  }
}

// ---------------- decode: out[p] = dot(z[a], z[b])  (16 lanes/pair, fdot2) ----------------
__global__ __launch_bounds__(256) void k_decode(const h2* __restrict__ zh2, const int* __restrict__ eli,
                                                float* __restrict__ out, int L) {
  int p = blockIdx.x * 16 + (threadIdx.x >> 4);
  int c2 = threadIdx.x & 15;
  if (p >= L) return;
  int a = eli[p], b = eli[L + p];
  h2 za = zh2[(size_t)a * 16 + c2];
  h2 zb = zh2[(size_t)b * 16 + c2];
  float v = __builtin_amdgcn_fdot2(za, zb, 0.f, false);
  #pragma unroll
  for (int off = 8; off >= 1; off >>= 1) v += __shfl_xor(v, off, 64);  // stays within 16-lane group
  if (c2 == 0) out[p] = v;
}

extern "C" void kernel_launch(void* const* d_in, const int* in_sizes, int n_in,
                              void* d_out, int out_size, void* d_ws, size_t ws_size,
                              hipStream_t stream) {
  const float* x   = (const float*)d_in[0];
  const int*   ei  = (const int*)d_in[1];
  const int*   eli = (const int*)d_in[2];
  const float* W1  = (const float*)d_in[3];
  const float* b1  = (const float*)d_in[4];
  const float* W2  = (const float*)d_in[5];
  const float* b2  = (const float*)d_in[6];
  float* out = (float*)d_out;

  const int N = in_sizes[0] / IN_C;
  const int E = in_sizes[1] / 2;
  const int L = in_sizes[2] / 2;
  const int* e_src = ei;
  const int* e_dst = ei + E;
  const int NB = (N + 255) >> BWL;

  char* p = (char*)d_ws;
  auto carve = [&](size_t bytes) -> void* {
    void* r = (void*)p;
    p += (bytes + 255) & ~(size_t)255;
    return r;
  };
  int*   ecnt      = (int*)  carve((size_t)N * 4);
  float* dinv      = (float*)carve((size_t)N * 4);
  int*   offsets   = (int*)  carve((size_t)N * 4);
  int*   bcnt      = (int*)  carve(NBMAX * 4);
  int*   bbase     = (int*)  carve((NBMAX + 1) * 4);
  int*   bcursor   = (int*)  carve(NBMAX * 4);
  _Float16* W1s    = (_Float16*)carve(256 * 128 * 2);         // 64 KB, fragment-swizzled
  _Float16* W2s    = (_Float16*)carve(32 * 256 * 2);          // 16 KB, fragment-swizzled
  int*   csr_src   = (int*)  carve((size_t)E * 4);            // 6.4 MB
  h2*    xh        = (h2*)   carve((size_t)N * IN_C * 2);     // 12.8 MB
  h2*    aggh      = (h2*)   carve(((size_t)N + 64) * IN_C * 2); // 12.8 MB (+pad rows for clamped loads)
  __half* h1h      = (__half*)carve(((size_t)N + 64) * H1 * 2);  // 25.6 MB
  unsigned long long* binned = (unsigned long long*)h1h;      // alias: dead before gemm1 writes h1h
  _Float16* h2h = (_Float16*)aggh;                            // alias: aggh dead after gemm1 reads it
  half4* h2h4 = (half4*)aggh;
  half4* zh4  = (half4*)((char*)aggh + (size_t)N * H2 * 2);
  h2*    zh2  = (h2*)zh4;

  const int B = 256;
  k_init<<<1, B, 0, stream>>>(bcnt, bcursor, NB);
  k_castw<<<128, B, 0, stream>>>(W1, W2, W1s, W2s);
  k_bin<<<(E + 2047) / 2048, B, 0, stream>>>(e_dst, bcnt, E, NB);
  k_scan_bkt<<<1, B, 0, stream>>>(bcnt, bbase, NB);
  k_scatter<<<(E + 4095) / 4096, B, 0, stream>>>(e_src, e_dst, bbase, bcursor, binned, E, NB);
  k_fill2<<<NB, B, 0, stream>>>(binned, bbase, csr_src, offsets, ecnt, dinv, N, NB);
  k_cast<<<(N * IN_C / 4 + B - 1) / B, B, 0, stream>>>((const float4*)x, dinv, xh, N * IN_C / 4);
  k_agg1<<<(N + 3) / 4, B, 0, stream>>>((const half8*)xh, dinv, ecnt, offsets, csr_src, (half8*)aggh, N);
  k_gemm1<<<(N + 63) / 64, B, 0, stream>>>((const _Float16*)aggh, W1s, b1, (_Float16*)h1h, N);
  k_gemm2<<<(N + 63) / 64, B, 0, stream>>>((const _Float16*)h1h, W2s, dinv, h2h, N);
  k_agg2<<<(N + 3) / 4, B, 0, stream>>>(h2h4, dinv, ecnt, offsets, csr_src, b2, zh4, N);
  k_decode<<<(L + 15) / 16, B, 0, stream>>>(zh2, eli, out, L);
}

// Round 10
// 278.428 us; speedup vs baseline: 1.0585x; 1.0585x over previous
//
#include <hip/hip_runtime.h>
#include <hip/hip_fp16.h>

#define IN_C 128
#define H1   256
#define H2   32
#define BWL  8              // bucket width = 256 nodes
#define NBMAX 256           // max buckets (N <= 65536)

typedef _Float16 half8 __attribute__((ext_vector_type(8)));
typedef _Float16 half4 __attribute__((ext_vector_type(4)));
typedef _Float16 h2    __attribute__((ext_vector_type(2)));
typedef float f32x4 __attribute__((ext_vector_type(4)));

// ---------------- init: zero bucket counters ----------------
__global__ __launch_bounds__(256) void k_init(int* bucket_cnt, int* bucket_cursor, int nb) {
  int i = blockIdx.x * blockDim.x + threadIdx.x;
  if (i < nb) { bucket_cnt[i] = 0; bucket_cursor[i] = 0; }
}

// ---------------- cast+scale x: xh[node] = (fp16)(x[node] * dinv[node])  (runs AFTER fill2) ----------------
__global__ __launch_bounds__(256) void k_cast(const float4* __restrict__ x4, const float* __restrict__ dinv,
                                              h2* __restrict__ xh, int n4) {
  int i = blockIdx.x * 256 + threadIdx.x;
  if (i < n4) {
    float4 v = x4[i];
    float dn = dinv[i >> 5];                 // 32 float4 per node (IN_C=128)
    h2 a, b;
    a[0] = (_Float16)(v.x * dn); a[1] = (_Float16)(v.y * dn);
    b[0] = (_Float16)(v.z * dn); b[1] = (_Float16)(v.w * dn);
    xh[2 * i] = a; xh[2 * i + 1] = b;
  }
}

// ---------------- cast weights into MFMA-fragment-swizzled fp16 layout ----------------
__global__ __launch_bounds__(256) void k_castw(const float* __restrict__ W1, const float* __restrict__ W2,
                                               _Float16* __restrict__ W1s, _Float16* __restrict__ W2s) {
  int i = blockIdx.x * 256 + threadIdx.x;
  if (i < 128 * 256) {
    int d = i >> 3, j = i & 7;
    int mrow = d & 15, quad = (d >> 4) & 3, ks = (d >> 6) & 3, nt = d >> 8;
    W1s[i] = (_Float16)W1[(ks * 32 + quad * 8 + j) * 256 + nt * 16 + mrow];
  }
  if (i < 32 * 256) {
    int d = i >> 3, j = i & 7;
    int mrow = d & 15, quad = (d >> 4) & 3, ks = (d >> 6) & 7, nt = d >> 9;
    W2s[i] = (_Float16)W2[(ks * 32 + quad * 8 + j) * 32 + nt * 16 + mrow];
  }
}

// ---------------- bucket histogram only (NO global per-node atomics) ----------------
__global__ __launch_bounds__(256) void k_bin(const int* __restrict__ dst, int* bucket_cnt, int e, int nb) {
  __shared__ int hist[NBMAX];
  for (int u = threadIdx.x; u < nb; u += 256) hist[u] = 0;
  __syncthreads();
  int base = blockIdx.x * 2048;
  #pragma unroll
  for (int j = 0; j < 8; j++) {
    int i = base + j * 256 + threadIdx.x;
    if (i < e) atomicAdd(&hist[dst[i] >> BWL], 1);
  }
  __syncthreads();
  for (int u = threadIdx.x; u < nb; u += 256) if (hist[u]) atomicAdd(&bucket_cnt[u], hist[u]);
}

// ---------------- scan bucket counts -> bucket_base (1 block) ----------------
__global__ __launch_bounds__(256) void k_scan_bkt(const int* __restrict__ bucket_cnt,
                                                  int* __restrict__ bucket_base, int nb) {
  __shared__ int tmp[256];
  int t = threadIdx.x;
  int b = (t < nb) ? bucket_cnt[t] : 0;
  tmp[t] = b; __syncthreads();
  for (int off = 1; off < 256; off <<= 1) {
    int x = (t >= off) ? tmp[t - off] : 0;
    __syncthreads();
    tmp[t] += x;
    __syncthreads();
  }
  if (t < nb) bucket_base[t] = tmp[t] - b;
  if (t == 255) bucket_base[nb] = tmp[255];
}

// ---------------- binned partition: (src,dst) packed 8B ----------------
__global__ __launch_bounds__(256) void k_scatter(const int* __restrict__ src, const int* __restrict__ dst,
                                                 const int* __restrict__ bucket_base, int* bucket_cursor,
                                                 unsigned long long* __restrict__ binned, int e, int nb) {
  __shared__ int hist[NBMAX];
  __shared__ int wbase[NBMAX];
  int t = threadIdx.x;
  for (int u = t; u < nb; u += 256) hist[u] = 0;
  __syncthreads();
  int base = blockIdx.x * 4096;
  int s_[16], d_[16];
  #pragma unroll
  for (int j = 0; j < 16; j++) {
    int i = base + j * 256 + t;
    if (i < e) {
      s_[j] = src[i]; d_[j] = dst[i];
      atomicAdd(&hist[d_[j] >> BWL], 1);
    } else d_[j] = -1;
  }
  __syncthreads();
  for (int u = t; u < nb; u += 256) {
    int c = hist[u];
    wbase[u] = (c > 0) ? (bucket_base[u] + atomicAdd(&bucket_cursor[u], c)) : 0;
  }
  __syncthreads();
  for (int u = t; u < nb; u += 256) hist[u] = 0;
  __syncthreads();
  #pragma unroll
  for (int j = 0; j < 16; j++) {
    if (d_[j] >= 0) {
      int b = d_[j] >> BWL;
      int r = atomicAdd(&hist[b], 1);
      binned[wbase[b] + r] = ((unsigned long long)(unsigned)d_[j] << 32) | (unsigned)s_[j];
    }
  }
}

// ---------------- CSR fill: one block/bucket. LDS degree count + prefix -> offsets/ecnt/dinv, place edges ----------------
__global__ __launch_bounds__(256) void k_fill2(const unsigned long long* __restrict__ binned,
                                               const int* __restrict__ bucket_base,
                                               int* __restrict__ csr_src,
                                               int* __restrict__ offsets, int* __restrict__ ecnt,
                                               float* __restrict__ dinv, int n, int nb) {
  __shared__ int cnt[256], pre[256], cur[256], loc[256];
  int b = blockIdx.x;
  int t = threadIdx.x;
  cnt[t] = 0; cur[t] = 0;
  __syncthreads();
  int start = bucket_base[b], end = bucket_base[b + 1];
  int node0 = b << BWL;
  for (int i = start + t; i < end; i += 256) {
    int d = (int)(binned[i] >> 32);
    atomicAdd(&cnt[d - node0], 1);
  }
  __syncthreads();
  int v = cnt[t];
  pre[t] = v; __syncthreads();
  for (int off = 1; off < 256; off <<= 1) {
    int x = (t >= off) ? pre[t - off] : 0;
    __syncthreads();
    pre[t] += x;
    __syncthreads();
  }
  int excl = pre[t] - v;
  loc[t] = excl;
  int node = node0 + t;
  if (node < n) {
    offsets[node] = start + excl;
    ecnt[node] = v;
    dinv[node] = rsqrtf((float)(v + 1));
  }
  __syncthreads();
  for (int i = start + t; i < end; i += 256) {
    unsigned long long sd = binned[i];
    int s = (int)(sd & 0xffffffffULL), d = (int)(sd >> 32);
    int li = d - node0;
    int p = atomicAdd(&cur[li], 1);
    csr_src[start + loc[li] + p] = s;
  }
}

// ---------------- layer-1 aggregation: wave/node; 4 edge-groups x 16 lanes; half8 (16B) gathers ----------------
__global__ __launch_bounds__(256) void k_agg1(const half8* __restrict__ xh8, const float* __restrict__ dinv,
                                              const int* __restrict__ ecnt, const int* __restrict__ offsets,
                                              const int* __restrict__ csr_src,
                                              half8* __restrict__ aggh8, int n) {
  int node = blockIdx.x * 4 + (threadIdx.x >> 6);
  int lane = threadIdx.x & 63;
  int g = lane >> 4;            // edge group 0..3
  int c8 = lane & 15;           // half8 index: channels c8*8..c8*8+7
  if (node >= n) return;
  float acc[8];
  #pragma unroll
  for (int k = 0; k < 8; k++) acc[k] = 0.f;
  int start = offsets[node];
  int cnt = ecnt[node];
  int j = 0;
  for (; j + 16 <= cnt; j += 16) {          // 16 edges/chunk: 4 per group
    int sA = csr_src[start + j + g];
    int sB = csr_src[start + j + 4 + g];
    int sC = csr_src[start + j + 8 + g];
    int sD = csr_src[start + j + 12 + g];
    half8 vA = xh8[(size_t)sA * 16 + c8];   // 16B/lane, 4 rows per instr
    half8 vB = xh8[(size_t)sB * 16 + c8];
    half8 vC = xh8[(size_t)sC * 16 + c8];
    half8 vD = xh8[(size_t)sD * 16 + c8];
    half8 s = (vA + vB) + (vC + vD);        // depth-2 fp16 tree
    #pragma unroll
    for (int k = 0; k < 8; k++) acc[k] += (float)s[k];
  }
  for (int t = j + g; t < cnt; t += 4) {    // tail: group-strided
    half8 v = xh8[(size_t)csr_src[start + t] * 16 + c8];
    #pragma unroll
    for (int k = 0; k < 8; k++) acc[k] += (float)v[k];
  }
  #pragma unroll
  for (int k = 0; k < 8; k++) {             // cross-group reduce (bits 4,5)
    acc[k] += __shfl_xor(acc[k], 16, 64);
    acc[k] += __shfl_xor(acc[k], 32, 64);
  }
  if (g == 0) {
    half8 selfv = xh8[(size_t)node * 16 + c8];
    float dn = dinv[node];
    half8 o;
    #pragma unroll
    for (int k = 0; k < 8; k++) o[k] = (_Float16)((acc[k] + (float)selfv[k]) * dn);
    aggh8[(size_t)node * 16 + c8] = o;
  }
}

// ---------------- GEMM1 (MFMA): h1 = relu(agg1 @ W1 + b1). Explicit bf[16] batch per K-step (16 loads in flight) ----------------
__global__ __launch_bounds__(256) void k_gemm1(const _Float16* __restrict__ aggh,
                                               const _Float16* __restrict__ W1s, const float* __restrict__ b1,
                                               _Float16* __restrict__ h1h, int n) {
  int wid = threadIdx.x >> 6, lane = threadIdx.x & 63;
  int quad = lane >> 4, mrow = lane & 15;
  int mbase = blockIdx.x * 64 + wid * 16;
  int node = mbase + mrow; if (node >= n) node = n - 1;   // clamp: garbage rows never stored
  const half8* A = (const half8*)aggh;                    // [node][k] ; 16 half8 per row
  const half8* B = (const half8*)W1s;                     // swizzled: frag(nt,ks) at [(nt*4+ks)*64 + lane]
  f32x4 acc[16];
  #pragma unroll
  for (int t = 0; t < 16; t++) acc[t] = (f32x4){0.f, 0.f, 0.f, 0.f};
  half8 a_cur = A[(size_t)node * 16 + quad];              // prefetch ks=0
  #pragma unroll
  for (int ks = 0; ks < 4; ks++) {                        // K = 4 x 32
    half8 bf[16];
    #pragma unroll
    for (int nt = 0; nt < 16; nt++) bf[nt] = B[(nt * 4 + ks) * 64 + lane];  // 16 independent loads
    half8 a = a_cur;
    if (ks < 3) a_cur = A[(size_t)node * 16 + (ks + 1) * 4 + quad];         // prefetch next A
    #pragma unroll
    for (int nt = 0; nt < 16; nt++)
      acc[nt] = __builtin_amdgcn_mfma_f32_16x16x32_f16(a, bf[nt], acc[nt], 0, 0, 0);
  }
  #pragma unroll
  for (int nt = 0; nt < 16; nt++) {
    int c = nt * 16 + mrow;                               // C/D: col = lane&15
    float bias = b1[c];
    #pragma unroll
    for (int r = 0; r < 4; r++) {
      int m = mbase + quad * 4 + r;                       // C/D: row = quad*4 + reg
      if (m < n) h1h[(size_t)m * H1 + c] = (_Float16)fmaxf(acc[nt][r] + bias, 0.f);
    }
  }
}

// ---------------- GEMM2 (MFMA): h2~ = (h1 @ W2) * dinv[m]. Explicit bf batch + A prefetch ----------------
__global__ __launch_bounds__(256) void k_gemm2(const _Float16* __restrict__ h1h,
                                               const _Float16* __restrict__ W2s, const float* __restrict__ dinv,
                                               _Float16* __restrict__ h2h, int n) {
  int wid = threadIdx.x >> 6, lane = threadIdx.x & 63;
  int quad = lane >> 4, mrow = lane & 15;
  int mbase = blockIdx.x * 64 + wid * 16;
  int node = mbase + mrow; if (node >= n) node = n - 1;
  const half8* A = (const half8*)h1h;                     // [node][k] ; 32 half8 per row
  const half8* B = (const half8*)W2s;                     // swizzled: frag(nt,ks) at [(nt*8+ks)*64 + lane]
  f32x4 acc[2];
  acc[0] = (f32x4){0.f, 0.f, 0.f, 0.f};
  acc[1] = (f32x4){0.f, 0.f, 0.f, 0.f};
  half8 bf[16];
  #pragma unroll
  for (int ks = 0; ks < 8; ks++) {                        // hoist ALL 16 B frags (16 KB table, L1)
    bf[2 * ks]     = B[(0 * 8 + ks) * 64 + lane];
    bf[2 * ks + 1] = B[(1 * 8 + ks) * 64 + lane];
  }
  half8 a_cur = A[(size_t)node * 32 + quad];
  #pragma unroll
  for (int ks = 0; ks < 8; ks++) {                        // K = 8 x 32
    half8 a = a_cur;
    if (ks < 7) a_cur = A[(size_t)node * 32 + (ks + 1) * 4 + quad];
    acc[0] = __builtin_amdgcn_mfma_f32_16x16x32_f16(a, bf[2 * ks],     acc[0], 0, 0, 0);
    acc[1] = __builtin_amdgcn_mfma_f32_16x16x32_f16(a, bf[2 * ks + 1], acc[1], 0, 0, 0);
  }
  #pragma unroll
  for (int nt = 0; nt < 2; nt++) {
    int c = nt * 16 + mrow;
    #pragma unroll
    for (int r = 0; r < 4; r++) {
      int m = mbase + quad * 4 + r;
      if (m < n) h2h[(size_t)m * H2 + c] = (_Float16)(acc[nt][r] * dinv[m]);  // pre-scaled for agg2
    }
  }
}

// ---------------- layer-2 aggregation: wave/node; 8 edge-groups x 8 lanes; half4 (8B) gathers ----------------
__global__ __launch_bounds__(256) void k_agg2(const half4* __restrict__ h2h4, const float* __restrict__ dinv,
                                              const int* __restrict__ ecnt, const int* __restrict__ offsets,
                                              const int* __restrict__ csr_src,
                                              const float* __restrict__ b2, half4* __restrict__ zh4, int n) {
  int node = blockIdx.x * 4 + (threadIdx.x >> 6);
  int lane = threadIdx.x & 63;
  int g = lane >> 3;            // edge group 0..7
  int c4 = lane & 7;            // half4 index: channels c4*4..c4*4+3
  if (node >= n) return;
  float acc[4];
  #pragma unroll
  for (int k = 0; k < 4; k++) acc[k] = 0.f;
  int start = offsets[node];
  int cnt = ecnt[node];
  int j = 0;
  for (; j + 16 <= cnt; j += 16) {          // 16 edges/chunk: 2 per group
    int sA = csr_src[start + j + g];
    int sB = csr_src[start + j + 8 + g];
    half4 vA = h2h4[(size_t)sA * 8 + c4];
    half4 vB = h2h4[(size_t)sB * 8 + c4];
    half4 s = vA + vB;
    #pragma unroll
    for (int k = 0; k < 4; k++) acc[k] += (float)s[k];
  }
  for (int t = j + g; t < cnt; t += 8) {
    half4 v = h2h4[(size_t)csr_src[start + t] * 8 + c4];
    #pragma unroll
    for (int k = 0; k < 4; k++) acc[k] += (float)v[k];
  }
  #pragma unroll
  for (int k = 0; k < 4; k++) {             // cross-group reduce (bits 3,4,5)
    acc[k] += __shfl_xor(acc[k], 8, 64);
    acc[k] += __shfl_xor(acc[k], 16, 64);
    acc[k] += __shfl_xor(acc[k], 32, 64);
  }
  if (g == 0) {
    half4 selfv = h2h4[(size_t)node * 8 + c4];
    float dn = dinv[node];
    half4 o;
    #pragma unroll
    for (int k = 0; k < 4; k++) o[k] = (_Float16)((acc[k] + (float)selfv[k]) * dn + b2[c4 * 4 + k]);
    zh4[(size_t)node * 8 + c4] = o;
  }
}

// ---------------- decode: out[p] = dot(z[a], z[b])  (16 lanes/pair, fdot2) ----------------
__global__ __launch_bounds__(256) void k_decode(const h2* __restrict__ zh2, const int* __restrict__ eli,
                                                float* __restrict__ out, int L) {
  int p = blockIdx.x * 16 + (threadIdx.x >> 4);
  int c2 = threadIdx.x & 15;
  if (p >= L) return;
  int a = eli[p], b = eli[L + p];
  h2 za = zh2[(size_t)a * 16 + c2];
  h2 zb = zh2[(size_t)b * 16 + c2];
  float v = __builtin_amdgcn_fdot2(za, zb, 0.f, false);
  #pragma unroll
  for (int off = 8; off >= 1; off >>= 1) v += __shfl_xor(v, off, 64);  // stays within 16-lane group
  if (c2 == 0) out[p] = v;
}

extern "C" void kernel_launch(void* const* d_in, const int* in_sizes, int n_in,
                              void* d_out, int out_size, void* d_ws, size_t ws_size,
                              hipStream_t stream) {
  const float* x   = (const float*)d_in[0];
  const int*   ei  = (const int*)d_in[1];
  const int*   eli = (const int*)d_in[2];
  const float* W1  = (const float*)d_in[3];
  const float* b1  = (const float*)d_in[4];
  const float* W2  = (const float*)d_in[5];
  const float* b2  = (const float*)d_in[6];
  float* out = (float*)d_out;

  const int N = in_sizes[0] / IN_C;
  const int E = in_sizes[1] / 2;
  const int L = in_sizes[2] / 2;
  const int* e_src = ei;
  const int* e_dst = ei + E;
  const int NB = (N + 255) >> BWL;

  char* p = (char*)d_ws;
  auto carve = [&](size_t bytes) -> void* {
    void* r = (void*)p;
    p += (bytes + 255) & ~(size_t)255;
    return r;
  };
  int*   ecnt      = (int*)  carve((size_t)N * 4);
  float* dinv      = (float*)carve((size_t)N * 4);
  int*   offsets   = (int*)  carve((size_t)N * 4);
  int*   bcnt      = (int*)  carve(NBMAX * 4);
  int*   bbase     = (int*)  carve((NBMAX + 1) * 4);
  int*   bcursor   = (int*)  carve(NBMAX * 4);
  _Float16* W1s    = (_Float16*)carve(256 * 128 * 2);         // 64 KB, fragment-swizzled
  _Float16* W2s    = (_Float16*)carve(32 * 256 * 2);          // 16 KB, fragment-swizzled
  int*   csr_src   = (int*)  carve((size_t)E * 4);            // 6.4 MB
  h2*    xh        = (h2*)   carve((size_t)N * IN_C * 2);     // 12.8 MB
  h2*    aggh      = (h2*)   carve(((size_t)N + 64) * IN_C * 2); // 12.8 MB (+pad rows for clamped loads)
  __half* h1h      = (__half*)carve(((size_t)N + 64) * H1 * 2);  // 25.6 MB
  unsigned long long* binned = (unsigned long long*)h1h;      // alias: dead before gemm1 writes h1h
  _Float16* h2h = (_Float16*)aggh;                            // alias: aggh dead after gemm1 reads it
  half4* h2h4 = (half4*)aggh;
  half4* zh4  = (half4*)((char*)aggh + (size_t)N * H2 * 2);
  h2*    zh2  = (h2*)zh4;

  const int B = 256;
  k_init<<<1, B, 0, stream>>>(bcnt, bcursor, NB);
  k_castw<<<128, B, 0, stream>>>(W1, W2, W1s, W2s);
  k_bin<<<(E + 2047) / 2048, B, 0, stream>>>(e_dst, bcnt, E, NB);
  k_scan_bkt<<<1, B, 0, stream>>>(bcnt, bbase, NB);
  k_scatter<<<(E + 4095) / 4096, B, 0, stream>>>(e_src, e_dst, bbase, bcursor, binned, E, NB);
  k_fill2<<<NB, B, 0, stream>>>(binned, bbase, csr_src, offsets, ecnt, dinv, N, NB);
  k_cast<<<(N * IN_C / 4 + B - 1) / B, B, 0, stream>>>((const float4*)x, dinv, xh, N * IN_C / 4);
  k_agg1<<<(N + 3) / 4, B, 0, stream>>>((const half8*)xh, dinv, ecnt, offsets, csr_src, (half8*)aggh, N);
  k_gemm1<<<(N + 63) / 64, B, 0, stream>>>((const _Float16*)aggh, W1s, b1, (_Float16*)h1h, N);
  k_gemm2<<<(N + 63) / 64, B, 0, stream>>>((const _Float16*)h1h, W2s, dinv, h2h, N);
  k_agg2<<<(N + 3) / 4, B, 0, stream>>>(h2h4, dinv, ecnt, offsets, csr_src, b2, zh4, N);
  k_decode<<<(L + 15) / 16, B, 0, stream>>>(zh2, eli, out, L);
}

// Round 11
// 262.623 us; speedup vs baseline: 1.1222x; 1.0602x over previous
//
#include <hip/hip_runtime.h>
#include <hip/hip_fp16.h>

#define IN_C 128
#define H1   256
#define H2   32
#define BWL  6              // bucket width = 64 nodes
#define NBMAX 1024          // max buckets (N <= 65536)

typedef _Float16 half8 __attribute__((ext_vector_type(8)));
typedef _Float16 half4 __attribute__((ext_vector_type(4)));
typedef _Float16 h2    __attribute__((ext_vector_type(2)));
typedef float f32x4 __attribute__((ext_vector_type(4)));

// ---------------- cast+scale x: xh[node] = (fp16)(x[node] * dinv[node])  (runs AFTER fill2) ----------------
__global__ __launch_bounds__(256) void k_cast(const float4* __restrict__ x4, const float* __restrict__ dinv,
                                              h2* __restrict__ xh, int n4) {
  int i = blockIdx.x * 256 + threadIdx.x;
  if (i < n4) {
    float4 v = x4[i];
    float dn = dinv[i >> 5];                 // 32 float4 per node (IN_C=128)
    h2 a, b;
    a[0] = (_Float16)(v.x * dn); a[1] = (_Float16)(v.y * dn);
    b[0] = (_Float16)(v.z * dn); b[1] = (_Float16)(v.w * dn);
    xh[2 * i] = a; xh[2 * i + 1] = b;
  }
}

// ---------------- fused: weight swizzle-cast + zero bucket counters ----------------
__global__ __launch_bounds__(256) void k_castw(const float* __restrict__ W1, const float* __restrict__ W2,
                                               _Float16* __restrict__ W1s, _Float16* __restrict__ W2s,
                                               int* bucket_cnt, int* bucket_cursor, int nb) {
  int i = blockIdx.x * 256 + threadIdx.x;
  if (i < 128 * 256) {
    int d = i >> 3, j = i & 7;
    int mrow = d & 15, quad = (d >> 4) & 3, ks = (d >> 6) & 3, nt = d >> 8;
    W1s[i] = (_Float16)W1[(ks * 32 + quad * 8 + j) * 256 + nt * 16 + mrow];
  }
  if (i < 32 * 256) {
    int d = i >> 3, j = i & 7;
    int mrow = d & 15, quad = (d >> 4) & 3, ks = (d >> 6) & 7, nt = d >> 9;
    W2s[i] = (_Float16)W2[(ks * 32 + quad * 8 + j) * 32 + nt * 16 + mrow];
  }
  if (i <= nb) { bucket_cnt[i] = 0; bucket_cursor[i] = 0; }
}

// ---------------- bucket histogram only (NO global per-node atomics) ----------------
__global__ __launch_bounds__(256) void k_bin(const int* __restrict__ dst, int* bucket_cnt, int e, int nb) {
  __shared__ int hist[NBMAX];
  for (int u = threadIdx.x; u < nb; u += 256) hist[u] = 0;
  __syncthreads();
  int base = blockIdx.x * 2048;
  #pragma unroll
  for (int j = 0; j < 8; j++) {
    int i = base + j * 256 + threadIdx.x;
    if (i < e) atomicAdd(&hist[dst[i] >> BWL], 1);
  }
  __syncthreads();
  for (int u = threadIdx.x; u < nb; u += 256) if (hist[u]) atomicAdd(&bucket_cnt[u], hist[u]);
}

// ---------------- scan bucket counts -> bucket_base (1 block, 4 elems/thread) ----------------
__global__ __launch_bounds__(256) void k_scan_bkt(const int* __restrict__ bucket_cnt,
                                                  int* __restrict__ bucket_base, int nb) {
  __shared__ int tsum[256];
  int t = threadIdx.x;
  int v[4]; int s = 0;
  #pragma unroll
  for (int k = 0; k < 4; k++) {
    int idx = t * 4 + k;
    int c = (idx < nb) ? bucket_cnt[idx] : 0;
    v[k] = s; s += c;
  }
  tsum[t] = s; __syncthreads();
  for (int off = 1; off < 256; off <<= 1) {
    int x = (t >= off) ? tsum[t - off] : 0;
    __syncthreads();
    tsum[t] += x;
    __syncthreads();
  }
  int excl = tsum[t] - s;
  #pragma unroll
  for (int k = 0; k < 4; k++) {
    int idx = t * 4 + k;
    if (idx < nb) bucket_base[idx] = excl + v[k];
  }
  if (t == 255) bucket_base[nb] = tsum[255];
}

// ---------------- binned partition: packed 4B records ((dst&63)<<16 | src), N<65536 ----------------
__global__ __launch_bounds__(256) void k_scatter(const int* __restrict__ src, const int* __restrict__ dst,
                                                 const int* __restrict__ bucket_base, int* bucket_cursor,
                                                 unsigned int* __restrict__ binned, int e, int nb) {
  __shared__ int hist[NBMAX];
  __shared__ int wbase[NBMAX];
  int t = threadIdx.x;
  for (int u = t; u < nb; u += 256) hist[u] = 0;
  __syncthreads();
  int base = blockIdx.x * 4096;
  int s_[16], d_[16];
  #pragma unroll
  for (int j = 0; j < 16; j++) {
    int i = base + j * 256 + t;
    if (i < e) {
      s_[j] = src[i]; d_[j] = dst[i];
      atomicAdd(&hist[d_[j] >> BWL], 1);
    } else d_[j] = -1;
  }
  __syncthreads();
  for (int u = t; u < nb; u += 256) {
    int c = hist[u];
    wbase[u] = (c > 0) ? (bucket_base[u] + atomicAdd(&bucket_cursor[u], c)) : 0;
  }
  __syncthreads();
  for (int u = t; u < nb; u += 256) hist[u] = 0;
  __syncthreads();
  #pragma unroll
  for (int j = 0; j < 16; j++) {
    if (d_[j] >= 0) {
      int b = d_[j] >> BWL;
      int r = atomicAdd(&hist[b], 1);
      binned[wbase[b] + r] = ((unsigned)(d_[j] & 63) << 16) | (unsigned)s_[j];
    }
  }
}

// ---------------- CSR fill: one block/bucket (64 nodes). LDS degree count + prefix; place edges ----------------
__global__ __launch_bounds__(256) void k_fill2(const unsigned int* __restrict__ binned,
                                               const int* __restrict__ bucket_base,
                                               int* __restrict__ csr_src,
                                               int* __restrict__ offsets, int* __restrict__ ecnt,
                                               float* __restrict__ dinv, int n, int nb) {
  __shared__ int cnt[64], pre[64], cur[64], loc[64];
  int b = blockIdx.x;
  int t = threadIdx.x;
  if (t < 64) { cnt[t] = 0; cur[t] = 0; }
  __syncthreads();
  int start = bucket_base[b], end = bucket_base[b + 1];
  int node0 = b << BWL;
  for (int i = start + t; i < end; i += 256) {
    int li = (int)(binned[i] >> 16);
    atomicAdd(&cnt[li], 1);
  }
  __syncthreads();
  int v = (t < 64) ? cnt[t] : 0;
  if (t < 64) pre[t] = v;
  __syncthreads();
  for (int off = 1; off < 64; off <<= 1) {
    int x = (t >= off && t < 64) ? pre[t - off] : 0;
    __syncthreads();
    if (t < 64) pre[t] += x;
    __syncthreads();
  }
  if (t < 64) {
    int excl = pre[t] - v;
    loc[t] = excl;
    int node = node0 + t;
    if (node < n) {
      offsets[node] = start + excl;
      ecnt[node] = v;
      dinv[node] = rsqrtf((float)(v + 1));
    }
  }
  __syncthreads();
  for (int i = start + t; i < end; i += 256) {
    unsigned int rec = binned[i];
    int li = (int)(rec >> 16);
    int p = atomicAdd(&cur[li], 1);
    csr_src[start + loc[li] + p] = (int)(rec & 0xFFFFu);
  }
}

// ---------------- layer-1 aggregation: wave/node; 4 edge-groups x 16 lanes; 32-edge chunks (8 gathers in flight) ----------------
__global__ __launch_bounds__(256) void k_agg1(const half8* __restrict__ xh8, const float* __restrict__ dinv,
                                              const int* __restrict__ ecnt, const int* __restrict__ offsets,
                                              const int* __restrict__ csr_src,
                                              half8* __restrict__ aggh8, int n) {
  int node = blockIdx.x * 4 + (threadIdx.x >> 6);
  int lane = threadIdx.x & 63;
  int g = lane >> 4;            // edge group 0..3
  int c8 = lane & 15;           // half8 index: channels c8*8..c8*8+7
  if (node >= n) return;
  float acc[8];
  #pragma unroll
  for (int k = 0; k < 8; k++) acc[k] = 0.f;
  int start = offsets[node];
  int cnt = ecnt[node];
  int j = 0;
  for (; j + 32 <= cnt; j += 32) {          // 32 edges/chunk: 8 gathers/lane in flight
    int s0 = csr_src[start + j + g],      s1 = csr_src[start + j + 4 + g];
    int s2 = csr_src[start + j + 8 + g],  s3 = csr_src[start + j + 12 + g];
    int s4 = csr_src[start + j + 16 + g], s5 = csr_src[start + j + 20 + g];
    int s6 = csr_src[start + j + 24 + g], s7 = csr_src[start + j + 28 + g];
    half8 v0 = xh8[(size_t)s0 * 16 + c8], v1 = xh8[(size_t)s1 * 16 + c8];
    half8 v2 = xh8[(size_t)s2 * 16 + c8], v3 = xh8[(size_t)s3 * 16 + c8];
    half8 v4 = xh8[(size_t)s4 * 16 + c8], v5 = xh8[(size_t)s5 * 16 + c8];
    half8 v6 = xh8[(size_t)s6 * 16 + c8], v7 = xh8[(size_t)s7 * 16 + c8];
    half8 s = (((v0 + v1) + (v2 + v3)) + ((v4 + v5) + (v6 + v7)));  // depth-3 fp16 tree
    #pragma unroll
    for (int k = 0; k < 8; k++) acc[k] += (float)s[k];
  }
  if (j + 16 <= cnt) {
    int s0 = csr_src[start + j + g],     s1 = csr_src[start + j + 4 + g];
    int s2 = csr_src[start + j + 8 + g], s3 = csr_src[start + j + 12 + g];
    half8 v0 = xh8[(size_t)s0 * 16 + c8], v1 = xh8[(size_t)s1 * 16 + c8];
    half8 v2 = xh8[(size_t)s2 * 16 + c8], v3 = xh8[(size_t)s3 * 16 + c8];
    half8 s = (v0 + v1) + (v2 + v3);
    #pragma unroll
    for (int k = 0; k < 8; k++) acc[k] += (float)s[k];
    j += 16;
  }
  for (int t = j + g; t < cnt; t += 4) {    // tail: group-strided
    half8 v = xh8[(size_t)csr_src[start + t] * 16 + c8];
    #pragma unroll
    for (int k = 0; k < 8; k++) acc[k] += (float)v[k];
  }
  #pragma unroll
  for (int k = 0; k < 8; k++) {             // cross-group reduce (bits 4,5)
    acc[k] += __shfl_xor(acc[k], 16, 64);
    acc[k] += __shfl_xor(acc[k], 32, 64);
  }
  if (g == 0) {
    half8 selfv = xh8[(size_t)node * 16 + c8];
    float dn = dinv[node];
    half8 o;
    #pragma unroll
    for (int k = 0; k < 8; k++) o[k] = (_Float16)((acc[k] + (float)selfv[k]) * dn);
    aggh8[(size_t)node * 16 + c8] = o;
  }
}

// ---------------- GEMM1 (MFMA): h1 = relu(agg1 @ W1 + b1). Explicit bf[16] batch per K-step ----------------
__global__ __launch_bounds__(256) void k_gemm1(const _Float16* __restrict__ aggh,
                                               const _Float16* __restrict__ W1s, const float* __restrict__ b1,
                                               _Float16* __restrict__ h1h, int n) {
  int wid = threadIdx.x >> 6, lane = threadIdx.x & 63;
  int quad = lane >> 4, mrow = lane & 15;
  int mbase = blockIdx.x * 64 + wid * 16;
  int node = mbase + mrow; if (node >= n) node = n - 1;   // clamp: garbage rows never stored
  const half8* A = (const half8*)aggh;                    // [node][k] ; 16 half8 per row
  const half8* B = (const half8*)W1s;                     // swizzled: frag(nt,ks) at [(nt*4+ks)*64 + lane]
  f32x4 acc[16];
  #pragma unroll
  for (int t = 0; t < 16; t++) acc[t] = (f32x4){0.f, 0.f, 0.f, 0.f};
  half8 a_cur = A[(size_t)node * 16 + quad];              // prefetch ks=0
  #pragma unroll
  for (int ks = 0; ks < 4; ks++) {                        // K = 4 x 32
    half8 bf[16];
    #pragma unroll
    for (int nt = 0; nt < 16; nt++) bf[nt] = B[(nt * 4 + ks) * 64 + lane];  // 16 independent loads
    half8 a = a_cur;
    if (ks < 3) a_cur = A[(size_t)node * 16 + (ks + 1) * 4 + quad];         // prefetch next A
    #pragma unroll
    for (int nt = 0; nt < 16; nt++)
      acc[nt] = __builtin_amdgcn_mfma_f32_16x16x32_f16(a, bf[nt], acc[nt], 0, 0, 0);
  }
  #pragma unroll
  for (int nt = 0; nt < 16; nt++) {
    int c = nt * 16 + mrow;                               // C/D: col = lane&15
    float bias = b1[c];
    #pragma unroll
    for (int r = 0; r < 4; r++) {
      int m = mbase + quad * 4 + r;                       // C/D: row = quad*4 + reg
      if (m < n) h1h[(size_t)m * H1 + c] = (_Float16)fmaxf(acc[nt][r] + bias, 0.f);
    }
  }
}

// ---------------- GEMM2 (MFMA): h2~ = (h1 @ W2) * dinv[m]. Explicit bf batch + A prefetch ----------------
__global__ __launch_bounds__(256) void k_gemm2(const _Float16* __restrict__ h1h,
                                               const _Float16* __restrict__ W2s, const float* __restrict__ dinv,
                                               _Float16* __restrict__ h2h, int n) {
  int wid = threadIdx.x >> 6, lane = threadIdx.x & 63;
  int quad = lane >> 4, mrow = lane & 15;
  int mbase = blockIdx.x * 64 + wid * 16;
  int node = mbase + mrow; if (node >= n) node = n - 1;
  const half8* A = (const half8*)h1h;                     // [node][k] ; 32 half8 per row
  const half8* B = (const half8*)W2s;                     // swizzled: frag(nt,ks) at [(nt*8+ks)*64 + lane]
  f32x4 acc[2];
  acc[0] = (f32x4){0.f, 0.f, 0.f, 0.f};
  acc[1] = (f32x4){0.f, 0.f, 0.f, 0.f};
  half8 bf[16];
  #pragma unroll
  for (int ks = 0; ks < 8; ks++) {                        // hoist ALL 16 B frags (16 KB table, L1)
    bf[2 * ks]     = B[(0 * 8 + ks) * 64 + lane];
    bf[2 * ks + 1] = B[(1 * 8 + ks) * 64 + lane];
  }
  half8 a_cur = A[(size_t)node * 32 + quad];
  #pragma unroll
  for (int ks = 0; ks < 8; ks++) {                        // K = 8 x 32
    half8 a = a_cur;
    if (ks < 7) a_cur = A[(size_t)node * 32 + (ks + 1) * 4 + quad];
    acc[0] = __builtin_amdgcn_mfma_f32_16x16x32_f16(a, bf[2 * ks],     acc[0], 0, 0, 0);
    acc[1] = __builtin_amdgcn_mfma_f32_16x16x32_f16(a, bf[2 * ks + 1], acc[1], 0, 0, 0);
  }
  #pragma unroll
  for (int nt = 0; nt < 2; nt++) {
    int c = nt * 16 + mrow;
    #pragma unroll
    for (int r = 0; r < 4; r++) {
      int m = mbase + quad * 4 + r;
      if (m < n) h2h[(size_t)m * H2 + c] = (_Float16)(acc[nt][r] * dinv[m]);  // pre-scaled for agg2
    }
  }
}

// ---------------- layer-2 aggregation: wave/node; 8 edge-groups x 8 lanes; 32-edge chunks ----------------
__global__ __launch_bounds__(256) void k_agg2(const half4* __restrict__ h2h4, const float* __restrict__ dinv,
                                              const int* __restrict__ ecnt, const int* __restrict__ offsets,
                                              const int* __restrict__ csr_src,
                                              const float* __restrict__ b2, half4* __restrict__ zh4, int n) {
  int node = blockIdx.x * 4 + (threadIdx.x >> 6);
  int lane = threadIdx.x & 63;
  int g = lane >> 3;            // edge group 0..7
  int c4 = lane & 7;            // half4 index: channels c4*4..c4*4+3
  if (node >= n) return;
  float acc[4];
  #pragma unroll
  for (int k = 0; k < 4; k++) acc[k] = 0.f;
  int start = offsets[node];
  int cnt = ecnt[node];
  int j = 0;
  for (; j + 32 <= cnt; j += 32) {          // 32 edges/chunk: 4 gathers/lane
    int sA = csr_src[start + j + g],      sB = csr_src[start + j + 8 + g];
    int sC = csr_src[start + j + 16 + g], sD = csr_src[start + j + 24 + g];
    half4 vA = h2h4[(size_t)sA * 8 + c4], vB = h2h4[(size_t)sB * 8 + c4];
    half4 vC = h2h4[(size_t)sC * 8 + c4], vD = h2h4[(size_t)sD * 8 + c4];
    half4 s = (vA + vB) + (vC + vD);
    #pragma unroll
    for (int k = 0; k < 4; k++) acc[k] += (float)s[k];
  }
  if (j + 16 <= cnt) {
    int sA = csr_src[start + j + g], sB = csr_src[start + j + 8 + g];
    half4 s = h2h4[(size_t)sA * 8 + c4] + h2h4[(size_t)sB * 8 + c4];
    #pragma unroll
    for (int k = 0; k < 4; k++) acc[k] += (float)s[k];
    j += 16;
  }
  for (int t = j + g; t < cnt; t += 8) {
    half4 v = h2h4[(size_t)csr_src[start + t] * 8 + c4];
    #pragma unroll
    for (int k = 0; k < 4; k++) acc[k] += (float)v[k];
  }
  #pragma unroll
  for (int k = 0; k < 4; k++) {             // cross-group reduce (bits 3,4,5)
    acc[k] += __shfl_xor(acc[k], 8, 64);
    acc[k] += __shfl_xor(acc[k], 16, 64);
    acc[k] += __shfl_xor(acc[k], 32, 64);
  }
  if (g == 0) {
    half4 selfv = h2h4[(size_t)node * 8 + c4];
    float dn = dinv[node];
    half4 o;
    #pragma unroll
    for (int k = 0; k < 4; k++) o[k] = (_Float16)((acc[k] + (float)selfv[k]) * dn + b2[c4 * 4 + k]);
    zh4[(size_t)node * 8 + c4] = o;
  }
}

// ---------------- decode: out[p] = dot(z[a], z[b])  (8 lanes/pair, half4 + fdot2) ----------------
__global__ __launch_bounds__(256) void k_decode(const half4* __restrict__ zh4, const int* __restrict__ eli,
                                                float* __restrict__ out, int L) {
  int p = blockIdx.x * 32 + (threadIdx.x >> 3);
  int c4 = threadIdx.x & 7;
  if (p >= L) return;
  int a = eli[p], b = eli[L + p];
  half4 za = zh4[(size_t)a * 8 + c4];
  half4 zb = zh4[(size_t)b * 8 + c4];
  h2 zal = {za[0], za[1]}, zah = {za[2], za[3]};
  h2 zbl = {zb[0], zb[1]}, zbh = {zb[2], zb[3]};
  float v = __builtin_amdgcn_fdot2(zal, zbl, __builtin_amdgcn_fdot2(zah, zbh, 0.f, false), false);
  #pragma unroll
  for (int off = 4; off >= 1; off >>= 1) v += __shfl_xor(v, off, 64);  // stays within 8-lane group
  if (c4 == 0) out[p] = v;
}

extern "C" void kernel_launch(void* const* d_in, const int* in_sizes, int n_in,
                              void* d_out, int out_size, void* d_ws, size_t ws_size,
                              hipStream_t stream) {
  const float* x   = (const float*)d_in[0];
  const int*   ei  = (const int*)d_in[1];
  const int*   eli = (const int*)d_in[2];
  const float* W1  = (const float*)d_in[3];
  const float* b1  = (const float*)d_in[4];
  const float* W2  = (const float*)d_in[5];
  const float* b2  = (const float*)d_in[6];
  float* out = (float*)d_out;

  const int N = in_sizes[0] / IN_C;   // 50000 < 65536 (4B packed records rely on this)
  const int E = in_sizes[1] / 2;
  const int L = in_sizes[2] / 2;
  const int* e_src = ei;
  const int* e_dst = ei + E;
  const int NB = (N + 63) >> BWL;     // 782 buckets of 64 nodes

  char* p = (char*)d_ws;
  auto carve = [&](size_t bytes) -> void* {
    void* r = (void*)p;
    p += (bytes + 255) & ~(size_t)255;
    return r;
  };
  int*   ecnt      = (int*)  carve((size_t)N * 4);
  float* dinv      = (float*)carve((size_t)N * 4);
  int*   offsets   = (int*)  carve((size_t)N * 4);
  int*   bcnt      = (int*)  carve((NBMAX + 1) * 4);
  int*   bbase     = (int*)  carve((NBMAX + 1) * 4);
  int*   bcursor   = (int*)  carve((NBMAX + 1) * 4);
  _Float16* W1s    = (_Float16*)carve(256 * 128 * 2);         // 64 KB, fragment-swizzled
  _Float16* W2s    = (_Float16*)carve(32 * 256 * 2);          // 16 KB, fragment-swizzled
  int*   csr_src   = (int*)  carve((size_t)E * 4);            // 6.4 MB
  h2*    xh        = (h2*)   carve((size_t)N * IN_C * 2);     // 12.8 MB
  h2*    aggh      = (h2*)   carve(((size_t)N + 64) * IN_C * 2); // 12.8 MB (+pad rows for clamped loads)
  __half* h1h      = (__half*)carve(((size_t)N + 64) * H1 * 2);  // 25.6 MB
  unsigned int* binned = (unsigned int*)h1h;                  // alias (6.4 MB): dead before gemm1 writes h1h
  _Float16* h2h = (_Float16*)aggh;                            // alias: aggh dead after gemm1 reads it
  half4* h2h4 = (half4*)aggh;
  half4* zh4  = (half4*)((char*)aggh + (size_t)N * H2 * 2);

  const int B = 256;
  k_castw<<<128, B, 0, stream>>>(W1, W2, W1s, W2s, bcnt, bcursor, NB);
  k_bin<<<(E + 2047) / 2048, B, 0, stream>>>(e_dst, bcnt, E, NB);
  k_scan_bkt<<<1, B, 0, stream>>>(bcnt, bbase, NB);
  k_scatter<<<(E + 4095) / 4096, B, 0, stream>>>(e_src, e_dst, bbase, bcursor, binned, E, NB);
  k_fill2<<<NB, B, 0, stream>>>(binned, bbase, csr_src, offsets, ecnt, dinv, N, NB);
  k_cast<<<(N * IN_C / 4 + B - 1) / B, B, 0, stream>>>((const float4*)x, dinv, xh, N * IN_C / 4);
  k_agg1<<<(N + 3) / 4, B, 0, stream>>>((const half8*)xh, dinv, ecnt, offsets, csr_src, (half8*)aggh, N);
  k_gemm1<<<(N + 63) / 64, B, 0, stream>>>((const _Float16*)aggh, W1s, b1, (_Float16*)h1h, N);
  k_gemm2<<<(N + 63) / 64, B, 0, stream>>>((const _Float16*)h1h, W2s, dinv, h2h, N);
  k_agg2<<<(N + 3) / 4, B, 0, stream>>>(h2h4, dinv, ecnt, offsets, csr_src, b2, zh4, N);
  k_decode<<<(L + 31) / 32, B, 0, stream>>>(zh4, eli, out, L);
}